// Round 3
// baseline (9323.459 us; speedup 1.0000x reference)
//
#include <hip/hip_runtime.h>
#include <cmath>

#define S_LEN 128
#define BATCH 32
#define HID   512
#define VOCAB 10000
#define MROWS (S_LEN * BATCH)   // 4096
#define HH    (HID * HID)

#define NBLK   128    // scan blocks: 64 col-slices x 2 batch-halves
#define GRPBLK 64     // blocks per barrier group (one batch-half)

// ---------------------------------------------------------------------------
// Tiled fp32 GEMM: C[M,N] = A[M,K] * B + bias[N]   (unchanged from round 2)
// ---------------------------------------------------------------------------
template<bool GATHER_A, bool B_KN>
__global__ __launch_bounds__(256) void gemm_kernel(
    const float* __restrict__ A, const int* __restrict__ tok,
    const float* __restrict__ Bmat, const float* __restrict__ bias,
    float* __restrict__ C, int M, int N, int K)
{
    __shared__ float As[32][68];
    __shared__ float Bs[32][68];
    __shared__ int   toks[64];

    const int tid = threadIdx.x;
    const int m0  = blockIdx.y * 64;
    const int n0  = blockIdx.x * 64;

    if (GATHER_A && tid < 64) toks[tid] = tok[m0 + tid];
    __syncthreads();

    const int tx = tid & 15;
    const int ty = tid >> 4;
    const int lr = tid >> 3;
    const int lc = (tid & 7) * 4;

    float acc[4][4] = {};

    for (int k0 = 0; k0 < K; k0 += 32) {
        #pragma unroll
        for (int rep = 0; rep < 2; rep++) {
            int r = lr + rep * 32;
            const float* arow;
            if (GATHER_A) arow = A + (size_t)toks[r] * K;
            else          arow = A + (size_t)(m0 + r) * K;
            float4 v = *(const float4*)(arow + k0 + lc);
            As[lc + 0][r] = v.x; As[lc + 1][r] = v.y;
            As[lc + 2][r] = v.z; As[lc + 3][r] = v.w;
        }
        if (B_KN) {
            int g    = n0 >> 9;
            int col0 = n0 & 511;
            const float* bbase = Bmat + (size_t)g * K * 512 + col0;
            int bc = (tid & 15) * 4;
            int bk = tid >> 4;
            #pragma unroll
            for (int rep = 0; rep < 2; rep++) {
                int kk = bk + rep * 16;
                float4 v = *(const float4*)(bbase + (size_t)(k0 + kk) * 512 + bc);
                *(float4*)&Bs[kk][bc] = v;
            }
        } else {
            #pragma unroll
            for (int rep = 0; rep < 2; rep++) {
                int r = lr + rep * 32;
                int n = n0 + r;
                float4 v = make_float4(0.f, 0.f, 0.f, 0.f);
                if (n < N) v = *(const float4*)(Bmat + (size_t)n * K + k0 + lc);
                Bs[lc + 0][r] = v.x; Bs[lc + 1][r] = v.y;
                Bs[lc + 2][r] = v.z; Bs[lc + 3][r] = v.w;
            }
        }
        __syncthreads();
        #pragma unroll
        for (int k = 0; k < 32; k++) {
            float4 a4 = *(const float4*)&As[k][ty * 4];
            float4 b4 = *(const float4*)&Bs[k][tx * 4];
            float av[4] = {a4.x, a4.y, a4.z, a4.w};
            float bv[4] = {b4.x, b4.y, b4.z, b4.w};
            #pragma unroll
            for (int i = 0; i < 4; i++)
                #pragma unroll
                for (int j = 0; j < 4; j++)
                    acc[i][j] = fmaf(av[i], bv[j], acc[i][j]);
        }
        __syncthreads();
    }
    #pragma unroll
    for (int i = 0; i < 4; i++) {
        int m = m0 + ty * 4 + i;
        #pragma unroll
        for (int j = 0; j < 4; j++) {
            int n = n0 + tx * 4 + j;
            if (n < N) C[(size_t)m * N + n] = acc[i][j] + bias[n];
        }
    }
}

// ---------------------------------------------------------------------------
// Device-scope barrier among GRPBLK blocks (generation counting).
// ---------------------------------------------------------------------------
__device__ __forceinline__ void group_barrier(unsigned* cnt, unsigned* gen)
{
    __syncthreads();
    if (threadIdx.x == 0) {
        __threadfence();   // release prior global writes device-wide
        unsigned g = __hip_atomic_load(gen, __ATOMIC_ACQUIRE, __HIP_MEMORY_SCOPE_AGENT);
        unsigned old = __hip_atomic_fetch_add(cnt, 1u, __ATOMIC_ACQ_REL, __HIP_MEMORY_SCOPE_AGENT);
        if (old == GRPBLK - 1) {
            __hip_atomic_store(cnt, 0u, __ATOMIC_RELAXED, __HIP_MEMORY_SCOPE_AGENT);
            __hip_atomic_fetch_add(gen, 1u, __ATOMIC_RELEASE, __HIP_MEMORY_SCOPE_AGENT);
        } else {
            while (__hip_atomic_load(gen, __ATOMIC_ACQUIRE, __HIP_MEMORY_SCOPE_AGENT) == g)
                __builtin_amdgcn_s_sleep(2);
        }
        __threadfence();   // acquire
    }
    __syncthreads();
}

#define FMA4(A, hb) do { A.x = fmaf(hb, wv.x, A.x); A.y = fmaf(hb, wv.y, A.y); \
                         A.z = fmaf(hb, wv.z, A.z); A.w = fmaf(hb, wv.w, A.w); } while (0)

// ---------------------------------------------------------------------------
// Cooperative GRU layer scan. 128 blocks = 64 col-slices x 2 batch-halves.
// Block (sIdx, half): phase1 computes rz cols [16s,16s+16) (one gate) for its
// 16 b; phase2 computes h-cols [8s,8s+8). Weights streamed from L2 (hot),
// batch reuse in registers (4b x 4c tiles). h kept transposed in LDS.
// Two 64-block barriers per step (halves are independent).
// ---------------------------------------------------------------------------
__global__ __launch_bounds__(256) void scan_coop_kernel(
    const float* __restrict__ ax, const float* __restrict__ Ul,
    float* __restrict__ hglob, float* __restrict__ rzbuf,
    float* __restrict__ hseq, float* __restrict__ hfin,
    unsigned* bar)
{
    __shared__ float hT[HID][20];     // h (then v) transposed: [k][b_local], pad 20
    __shared__ float part[4096];      // k-split partials (shared ph1/ph2)
    __shared__ float hold[8][16];     // old h for blend: [c_local][b_local]

    const int tid  = threadIdx.x;
    const int bid  = blockIdx.x;
    const int half = bid & 1;
    const int sIdx = bid >> 1;
    const int lane = tid & 63;
    const int wave = tid >> 6;

    unsigned* cnt = bar + half * 64;
    unsigned* gen = bar + half * 64 + 32;

    // phase1 mapping: 16 tiles (4bg x 4cg) x 16 k-slices (32 k each)
    const int cg1 = lane & 3;
    const int bg1 = (lane >> 2) & 3;
    const int ks1 = wave * 4 + (lane >> 4);
    const int g1  = sIdx >> 5;                 // gate 0 (r) or 1 (z)
    const int c1b = (sIdx & 31) * 16;          // col base within gate
    const float* w1 = Ul + (size_t)g1 * HH + c1b + 4 * cg1;

    // phase2 mapping: 8 tiles (4bg x 2cg) x 32 k-slices (16 k each)
    const int cg2 = lane & 1;
    const int bg2 = (lane >> 1) & 3;
    const int ks2 = wave * 8 + (lane >> 3);
    const float* w2 = Ul + (size_t)2 * HH + 8 * sIdx + 4 * cg2;

    // refresh / v mapping: b fast (LDS-friendly), 16 b x 16 k-quarters
    const int vb  = tid & 15;
    const int vk  = tid >> 4;
    const int vbg = 16 * half + vb;

    for (int t = 0; t < S_LEN; t++) {
        // ---- h refresh: hglob -> hT (transpose) ----
        {
            const float* src = hglob + (size_t)vbg * HID + vk * 32;
            #pragma unroll
            for (int kk = 0; kk < 32; kk += 4) {
                float4 f = *(const float4*)(src + kk);
                int k = vk * 32 + kk;
                hT[k + 0][vb] = f.x; hT[k + 1][vb] = f.y;
                hT[k + 2][vb] = f.z; hT[k + 3][vb] = f.w;
            }
        }
        __syncthreads();

        // ---- save old h for the blend (block's 8 h-cols) ----
        if (tid < 128) {
            int cl = tid >> 4, bl = tid & 15;
            hold[cl][bl] = hT[8 * sIdx + cl][bl];
        }

        // ---- phase 1: r/z partial GEMM (weights from L2, h from LDS) ----
        {
            float4 a0 = {0,0,0,0}, a1 = {0,0,0,0}, a2 = {0,0,0,0}, a3 = {0,0,0,0};
            const int k0 = ks1 * 32;
            const float* wp = w1 + (size_t)k0 * HID;
            #pragma unroll 4
            for (int k = 0; k < 32; k++) {
                float4 wv = *(const float4*)(wp + (size_t)k * HID);
                float4 hv = *(const float4*)&hT[k0 + k][4 * bg1];
                FMA4(a0, hv.x); FMA4(a1, hv.y); FMA4(a2, hv.z); FMA4(a3, hv.w);
            }
            int base = ks1 * 256 + (4 * bg1) * 16 + 4 * cg1;
            *(float4*)&part[base +  0] = a0;
            *(float4*)&part[base + 16] = a1;
            *(float4*)&part[base + 32] = a2;
            *(float4*)&part[base + 48] = a3;
        }
        __syncthreads();

        // ---- phase 1 reduce + sigmoid -> rzbuf (global) ----
        {
            int bl = tid >> 4, cl = tid & 15;
            float s = 0.f;
            #pragma unroll
            for (int ks = 0; ks < 16; ks++) s += part[ks * 256 + tid];
            int bglob = 16 * half + bl;
            int colg  = g1 * 512 + c1b + cl;
            float pre = ax[(size_t)(t * BATCH + bglob) * 1536 + colg] + s;
            rzbuf[(size_t)bglob * 1024 + colg] = 1.f / (1.f + __expf(-pre));
        }

        group_barrier(cnt, gen);   // rz visible to all blocks of this half

        // ---- v = r * h  (in place on hT, same-thread elements) ----
        {
            const float* rp = rzbuf + (size_t)vbg * 1024 + vk * 32;
            #pragma unroll
            for (int kk = 0; kk < 32; kk += 4) {
                float4 r4 = *(const float4*)(rp + kk);
                int k = vk * 32 + kk;
                hT[k + 0][vb] *= r4.x; hT[k + 1][vb] *= r4.y;
                hT[k + 2][vb] *= r4.z; hT[k + 3][vb] *= r4.w;
            }
        }
        __syncthreads();

        // ---- phase 2: h_hat partial GEMM ----
        {
            float4 a0 = {0,0,0,0}, a1 = {0,0,0,0}, a2 = {0,0,0,0}, a3 = {0,0,0,0};
            const int k0 = ks2 * 16;
            const float* wp = w2 + (size_t)k0 * HID;
            #pragma unroll 4
            for (int k = 0; k < 16; k++) {
                float4 wv = *(const float4*)(wp + (size_t)k * HID);
                float4 hv = *(const float4*)&hT[k0 + k][4 * bg2];
                FMA4(a0, hv.x); FMA4(a1, hv.y); FMA4(a2, hv.z); FMA4(a3, hv.w);
            }
            int base = ks2 * 128 + (4 * bg2) * 8 + 4 * cg2;
            *(float4*)&part[base +  0] = a0;
            *(float4*)&part[base +  8] = a1;
            *(float4*)&part[base + 16] = a2;
            *(float4*)&part[base + 24] = a3;
        }
        __syncthreads();

        // ---- phase 2 reduce + tanh + blend -> hglob, hseq (+hfin at t end) ----
        if (tid < 128) {
            int bl = tid >> 3, cl = tid & 7;
            float s = 0.f;
            #pragma unroll
            for (int ks = 0; ks < 32; ks++) s += part[ks * 128 + tid];
            int bglob = 16 * half + bl;
            int colg  = 8 * sIdx + cl;
            size_t row = (size_t)(t * BATCH + bglob);
            float pre = ax[row * 1536 + 1024 + colg] + s;
            float e2  = __expf(2.f * pre);
            float hh  = 1.f - 2.f / (e2 + 1.f);     // tanh
            float z   = rzbuf[(size_t)bglob * 1024 + 512 + colg];
            float hn  = (1.f - z) * hold[cl][bl] + z * hh;
            hglob[(size_t)bglob * HID + colg] = hn;
            hseq[row * HID + colg] = hn;
            if (t == S_LEN - 1) hfin[(size_t)bglob * HID + colg] = hn;
        }

        group_barrier(cnt, gen);   // h' visible before next refresh
    }
}

// ---------------------------------------------------------------------------
extern "C" void kernel_launch(void* const* d_in, const int* in_sizes, int n_in,
                              void* d_out, int out_size, void* d_ws, size_t ws_size,
                              hipStream_t stream)
{
    const int*   tokens = (const int*)  d_in[0];   // [S,B]
    const float* h0     = (const float*)d_in[1];   // [L,B,H]
    const float* emb    = (const float*)d_in[2];   // [V,H]
    const float* Wx     = (const float*)d_in[3];   // [L,3,H,H]
    const float* bx     = (const float*)d_in[4];   // [L,3,H]
    const float* U      = (const float*)d_in[5];   // [L,3,H,H]
    const float* Wy     = (const float*)d_in[6];   // [V,H]
    const float* by     = (const float*)d_in[7];   // [V]
    float*       out    = (float*)d_out;

    float* ws    = (float*)d_ws;
    float* axbuf = ws;                                 // MROWS*1536
    float* hseq  = axbuf + (size_t)MROWS * 1536;       // MROWS*512
    float* hglob = hseq  + (size_t)MROWS * HID;        // B*H
    float* rzbuf = hglob + BATCH * HID;                // B*1024
    unsigned* bar = (unsigned*)(rzbuf + BATCH * 1024); // 128 uints

    const size_t logits_sz = (size_t)MROWS * VOCAB;
    float* hfin0 = out + logits_sz;
    float* hfin1 = out + logits_sz + BATCH * HID;

    hipMemsetAsync(bar, 0, 512, stream);

    // ax0 = emb[tokens] @ Wx[0] + bx[0]
    gemm_kernel<true, true><<<dim3(24, 64), 256, 0, stream>>>(
        emb, tokens, Wx, bx, axbuf, MROWS, 1536, HID);

    // layer-0 scan
    hipMemcpyAsync(hglob, h0, BATCH * HID * sizeof(float),
                   hipMemcpyDeviceToDevice, stream);
    scan_coop_kernel<<<NBLK, 256, 0, stream>>>(
        axbuf, U, hglob, rzbuf, hseq, hfin0, bar);

    // ax1 = hseq @ Wx[1] + bx[1]
    gemm_kernel<false, true><<<dim3(24, 64), 256, 0, stream>>>(
        hseq, nullptr, Wx + 3 * HH, bx + 1536, axbuf, MROWS, 1536, HID);

    // layer-1 scan (overwrites hseq with tops)
    hipMemcpyAsync(hglob, h0 + BATCH * HID, BATCH * HID * sizeof(float),
                   hipMemcpyDeviceToDevice, stream);
    scan_coop_kernel<<<NBLK, 256, 0, stream>>>(
        axbuf, U + 3 * HH, hglob, rzbuf, hseq, hfin1, bar);

    // logits = tops @ Wy^T + by
    gemm_kernel<false, false><<<dim3(157, 64), 256, 0, stream>>>(
        hseq, nullptr, Wy, by, out, MROWS, VOCAB, HID);
}